// Round 13
// baseline (274.724 us; speedup 1.0000x reference)
//
#include <hip/hip_runtime.h>
#include <cstdint>
#include <cstddef>

#define BB 4
#define SS 2048
#define DIMM 1024
#define NH 16
#define DH 64
#define MT 8192   // B*S

typedef __attribute__((ext_vector_type(8))) short bf16x8;
typedef __attribute__((ext_vector_type(4))) float f32x4;
typedef __attribute__((ext_vector_type(4))) unsigned short u16x4;
typedef __attribute__((ext_vector_type(4))) unsigned int uint32x4;

#define MFMA_BF16(a, b, c) __builtin_amdgcn_mfma_f32_16x16x32_bf16(a, b, c, 0, 0, 0)

// log2(e) * 0.125 (attention scale folded into Wq/bq; softmax in base-2)
#define QSCALE 0.1803368801111137f

// packed f32x2 -> bf16x2 (RNE), single VALU op
__device__ __forceinline__ unsigned int cvtpk(float lo, float hi) {
    unsigned int r;
    asm("v_cvt_pk_bf16_f32 %0, %1, %2" : "=v"(r) : "v"(lo), "v"(hi));
    return r;
}

// single f32 -> bf16 bits (RNE) via cvt_pk, 1 VALU op
__device__ __forceinline__ unsigned short f2b1(float f) {
    return (unsigned short)cvtpk(f, f);
}

// 2^x via v_exp_f32 (hardware base-2 exp)
__device__ __forceinline__ float fexp2(float x) {
    float r;
    asm("v_exp_f32 %0, %1" : "=v"(r) : "v"(x));
    return r;
}

// async 16B global -> LDS (dest = wave-uniform base + lane*16)
__device__ __forceinline__ void gload16(const void* g, void* l) {
    __builtin_amdgcn_global_load_lds(
        (const __attribute__((address_space(1))) unsigned int*)g,
        (__attribute__((address_space(3))) unsigned int*)l, 16, 0, 0);
}

// XOR-swizzled byte offset for a [rows][64 bf16] tile (8 chunks of 16B/row)
__device__ __forceinline__ int swzb(int row, int cb) {
    return row * 128 + (((cb) ^ (row & 7)) << 4);
}

// ============================================================================
// Fused preprocessing, one launch, 78848 blocks x 256:
//  [0, 12288)      : fp32 -> bf16 convert of q/k/v (4096 blocks each)
//  [12288, 77824)  : mask int32 [B][S][S] -> bit-packed uint64 (65536 blocks)
//  [77824, 78848)  : W fp32 -> WT bf16 [n][k] transpose x4 (256 blocks each)
// ============================================================================
__global__ __launch_bounds__(256)
void prep_kernel(const float* __restrict__ q, const float* __restrict__ k,
                 const float* __restrict__ v,
                 unsigned short* __restrict__ Qb, unsigned short* __restrict__ Kb,
                 unsigned short* __restrict__ Vb,
                 const int* __restrict__ mask, unsigned long long* __restrict__ mp,
                 const float* __restrict__ Wq, const float* __restrict__ Wk,
                 const float* __restrict__ Wv, const float* __restrict__ Wo,
                 unsigned short* __restrict__ WT3, unsigned short* __restrict__ WTo)
{
    __shared__ unsigned short T[64][72];
    const int tid = threadIdx.x;
    const int bid = blockIdx.x;

    if (bid < 12288) {
        // ---- q/k/v fp32 -> bf16
        const int which = bid >> 12;
        const float* src = (which == 0) ? q : (which == 1) ? k : v;
        unsigned short* dst = (which == 0) ? Qb : (which == 1) ? Kb : Vb;
        const size_t i = ((size_t)(bid & 4095) * 256 + tid) * 8;
        const float4 lo = *reinterpret_cast<const float4*>(src + i);
        const float4 hi = *reinterpret_cast<const float4*>(src + i + 4);
        uint32x4 w = {cvtpk(lo.x, lo.y), cvtpk(lo.z, lo.w),
                      cvtpk(hi.x, hi.y), cvtpk(hi.z, hi.w)};
        *reinterpret_cast<uint32x4*>(dst + i) = w;
    } else if (bid < 77824) {
        // ---- mask bit-pack via ballot
        const size_t i = (size_t)(bid - 12288) * 256 + tid;
        const unsigned long long bal = __ballot(mask[i] != 0);
        if ((tid & 63) == 0) mp[i >> 6] = bal;
    } else {
        // ---- weight transpose + convert (+ QSCALE fold for Wq)
        const int wb = bid - 77824;
        const int which = wb >> 8;
        const float* W = (which == 0) ? Wq : (which == 1) ? Wk : (which == 2) ? Wv : Wo;
        unsigned short* WT = (which < 3) ? (WT3 + (size_t)which * DIMM * DIMM) : WTo;
        const float scale = (which == 0) ? QSCALE : 1.0f;
        const int within = wb & 255;
        const int n0 = (within & 15) * 64, k0 = (within >> 4) * 64;
#pragma unroll
        for (int it = 0; it < 4; ++it) {
            const int c = tid + it * 256;
            const int row = c >> 4, c4 = (c & 15) * 4;
            const float4 vv = *reinterpret_cast<const float4*>(
                &W[(size_t)(k0 + row) * DIMM + n0 + c4]);
            T[row][c4 + 0] = f2b1(vv.x * scale);
            T[row][c4 + 1] = f2b1(vv.y * scale);
            T[row][c4 + 2] = f2b1(vv.z * scale);
            T[row][c4 + 3] = f2b1(vv.w * scale);
        }
        __syncthreads();
#pragma unroll
        for (int it = 0; it < 4; ++it) {
            const int c = tid + it * 256;
            const int n = c >> 4, k4 = (c & 15) * 4;
            u16x4 o;
            o[0] = T[k4 + 0][n];
            o[1] = T[k4 + 1][n];
            o[2] = T[k4 + 2][n];
            o[3] = T[k4 + 3][n];
            *reinterpret_cast<u16x4*>(&WT[(size_t)(n0 + n) * DIMM + k0 + k4]) = o;
        }
    }
}

// ============================================================================
// Fused QKV projection GEMM, 1536 blocks. Regions SEQUENTIAL in bid
// (region = bid>>9) with the proven per-region swizzle on bid&511; since
// 512 % 8 == 0, every block lands on the same XCD as the 3-launch version
// (only the inter-launch tails are removed). 128x128 tile, BK=32, 4 waves,
// 16x16x32 bf16 MFMA, gload16 staging for both operands.
// Region 0,1 (Q,K): Y bf16 head-interleaved [B,H,S,Dh] (Q scaled by QSCALE).
// Region 2   (V)  : Y bf16 VhT [B,H,Dh,S'] with the PV k-permutation on s.
// ============================================================================
__global__ __launch_bounds__(256)
void gemm_qkv_kernel(const unsigned short* __restrict__ Qb,
                     const unsigned short* __restrict__ Kb,
                     const unsigned short* __restrict__ Vb,
                     const unsigned short* __restrict__ WT3,
                     const float* __restrict__ bq, const float* __restrict__ bk,
                     const float* __restrict__ bv,
                     unsigned short* __restrict__ Qh, unsigned short* __restrict__ Kh,
                     unsigned short* __restrict__ VhT)
{
    __shared__ __align__(16) unsigned short As[128 * 32];
    __shared__ __align__(16) unsigned short Bs[128 * 32];
    const int tid = threadIdx.x;
    const int w = tid >> 6, l = tid & 63;
    const int g = l >> 4, li = l & 15;
    const int bid = blockIdx.x;
    const int region = bid >> 9;
    const int rl = bid & 511;
    const int swz = (rl & 7) * 64 + (rl >> 3);
    const int m0 = (swz >> 3) * 128, n0 = (swz & 7) * 128;
    const int wm0 = (w >> 1) * 64, wn0 = (w & 1) * 64;

    const unsigned short* A = (region == 0) ? Qb : (region == 1) ? Kb : Vb;
    const unsigned short* BT = WT3 + (size_t)region * (DIMM * DIMM);

    const f32x4 fzero = {0.f, 0.f, 0.f, 0.f};
    f32x4 acc[4][4];
#pragma unroll
    for (int i = 0; i < 4; ++i)
#pragma unroll
        for (int j = 0; j < 4; ++j) acc[i][j] = fzero;

    for (int k0 = 0; k0 < DIMM; k0 += 32) {
#pragma unroll
        for (int it = 0; it < 2; ++it) {
            const int c = it * 256 + w * 64 + l;
            const int row = c >> 2, cb = c & 3;
            gload16(&A[(size_t)(m0 + row) * DIMM + k0 + cb * 8],
                    &As[(it * 256 + w * 64) * 8]);
        }
#pragma unroll
        for (int it = 0; it < 2; ++it) {
            const int c = it * 256 + w * 64 + l;
            const int row = c >> 2, cb = c & 3;
            gload16(&BT[(size_t)(n0 + row) * DIMM + k0 + cb * 8],
                    &Bs[(it * 256 + w * 64) * 8]);
        }
        __syncthreads();

        bf16x8 af[4], bf[4];
#pragma unroll
        for (int mb = 0; mb < 4; ++mb)
            af[mb] = *reinterpret_cast<const bf16x8*>(&As[(wm0 + mb * 16 + li) * 32 + g * 8]);
#pragma unroll
        for (int nb = 0; nb < 4; ++nb)
            bf[nb] = *reinterpret_cast<const bf16x8*>(&Bs[(wn0 + nb * 16 + li) * 32 + g * 8]);
#pragma unroll
        for (int mb = 0; mb < 4; ++mb)
#pragma unroll
            for (int nb = 0; nb < 4; ++nb)
                acc[mb][nb] = MFMA_BF16(af[mb], bf[nb], acc[mb][nb]);
        __syncthreads();
    }

    const float* bias = (region == 0) ? bq : (region == 1) ? bk : bv;
    const float bscale = (region == 0) ? QSCALE : 1.0f;
    float bv4[4];
#pragma unroll
    for (int nb = 0; nb < 4; ++nb)
        bv4[nb] = bias[n0 + wn0 + nb * 16 + li] * bscale;

    unsigned short* dst = (region == 0) ? Qh : (region == 1) ? Kh : VhT;
#pragma unroll
    for (int mb = 0; mb < 4; ++mb) {
#pragma unroll
        for (int r = 0; r < 4; ++r) {
            const int row_g = m0 + wm0 + mb * 16 + g * 4 + r;
#pragma unroll
            for (int nb = 0; nb < 4; ++nb) {
                const int col = n0 + wn0 + nb * 16 + li;
                const float val = acc[mb][nb][r] + bv4[nb];
                const int bb = row_g >> 11, s = row_g & 2047;
                const int hh = col >> 6, dd = col & 63;
                if (region < 2) {
                    dst[(((size_t)(bb * NH + hh)) * SS + s) * DH + dd] = f2b1(val);
                } else {   // VhT [b,h,d,s'] with PV k-permutation on s
                    const int st = s & 63;
                    const int sp = (st & 32) + ((st >> 2) & 3) * 8 + ((st & 16) >> 2) + (st & 3);
                    dst[(((size_t)(bb * NH + hh)) * DH + dd) * SS + (s & ~63) + sp] = f2b1(val);
                }
            }
        }
    }
}

// ============================================================================
// Output GEMM: A bf16 head-interleaved (ctx, gload16), Y fp32 row-major.
// 512 blocks, XCD-aware swizzle.
// ============================================================================
__global__ __launch_bounds__(256)
void gemm_out_kernel(const unsigned short* __restrict__ Ax, const unsigned short* __restrict__ BT,
                     const float* __restrict__ bias, float* __restrict__ Y)
{
    __shared__ __align__(16) unsigned short As[128 * 32];
    __shared__ __align__(16) unsigned short Bs[128 * 32];
    const int tid = threadIdx.x;
    const int w = tid >> 6, l = tid & 63;
    const int g = l >> 4, li = l & 15;
    const int bid = blockIdx.x;
    const int swz = (bid & 7) * 64 + (bid >> 3);
    const int m0 = (swz >> 3) * 128, n0 = (swz & 7) * 128;
    const int wm0 = (w >> 1) * 64, wn0 = (w & 1) * 64;

    const f32x4 fzero = {0.f, 0.f, 0.f, 0.f};
    f32x4 acc[4][4];
#pragma unroll
    for (int i = 0; i < 4; ++i)
#pragma unroll
        for (int j = 0; j < 4; ++j) acc[i][j] = fzero;

    for (int k0 = 0; k0 < DIMM; k0 += 32) {
        const int h = k0 >> 6;
#pragma unroll
        for (int it = 0; it < 2; ++it) {
            const int c = it * 256 + w * 64 + l;
            const int row = c >> 2, cb = c & 3;
            const int m = m0 + row;
            const int bb = m >> 11, s = m & 2047;
            gload16(&Ax[(((size_t)(bb * NH + h)) * SS + s) * DH + (k0 & 63) + cb * 8],
                    &As[(it * 256 + w * 64) * 8]);
        }
#pragma unroll
        for (int it = 0; it < 2; ++it) {
            const int c = it * 256 + w * 64 + l;
            const int row = c >> 2, cb = c & 3;
            gload16(&BT[(size_t)(n0 + row) * DIMM + k0 + cb * 8],
                    &Bs[(it * 256 + w * 64) * 8]);
        }
        __syncthreads();

        bf16x8 af[4], bf[4];
#pragma unroll
        for (int mb = 0; mb < 4; ++mb)
            af[mb] = *reinterpret_cast<const bf16x8*>(&As[(wm0 + mb * 16 + li) * 32 + g * 8]);
#pragma unroll
        for (int nb = 0; nb < 4; ++nb)
            bf[nb] = *reinterpret_cast<const bf16x8*>(&Bs[(wn0 + nb * 16 + li) * 32 + g * 8]);
#pragma unroll
        for (int mb = 0; mb < 4; ++mb)
#pragma unroll
            for (int nb = 0; nb < 4; ++nb)
                acc[mb][nb] = MFMA_BF16(af[mb], bf[nb], acc[mb][nb]);
        __syncthreads();
    }

    float bv4[4];
#pragma unroll
    for (int nb = 0; nb < 4; ++nb)
        bv4[nb] = bias[n0 + wn0 + nb * 16 + li];

#pragma unroll
    for (int mb = 0; mb < 4; ++mb) {
#pragma unroll
        for (int r = 0; r < 4; ++r) {
            const int row_g = m0 + wm0 + mb * 16 + g * 4 + r;
#pragma unroll
            for (int nb = 0; nb < 4; ++nb) {
                const int col = n0 + wn0 + nb * 16 + li;
                Y[(size_t)row_g * DIMM + col] = acc[mb][nb][r] + bv4[nb];
            }
        }
    }
}

// ============================================================================
// Flash attention (round-11 verified form, verbatim): grid (h, qt, b) pins
// each head to one XCD (bid%8 == h%8; per-XCD K/V set = 4MB = L2). K/V
// double-buffered with async prefetch into the other buffer; one
// __syncthreads per tile (drains vmcnt). No-max base-2 softmax, l-sum via
// MFMA ones-fragment, mask as packed-AND LDS LUT.
// ============================================================================
__global__ __launch_bounds__(256, 4)
void flash_kernel(const unsigned short* __restrict__ Qh, const unsigned short* __restrict__ Kh,
                  const unsigned short* __restrict__ VhT, const unsigned long long* __restrict__ maskp,
                  unsigned short* __restrict__ Ctx)
{
    const int h = blockIdx.x, qt = blockIdx.y, b = blockIdx.z;
    const int tid = threadIdx.x;
    const int w = tid >> 6, l = tid & 63;
    const int g = l >> 4, li = l & 15;

    // 32 KB: [K buf0 | K buf1 | V buf0 | V buf1], each 64x64 bf16 (8 KB).
    __shared__ __align__(16) unsigned short smem[4 * 64 * 64];
    __shared__ unsigned int LUT4[4];   // 2-bit mask -> half-word AND mask

    const int q0 = qt * 128;
    const size_t hb = ((size_t)(b * NH + h)) * (size_t)(SS * DH);

    if (tid < 4) LUT4[tid] = ((tid & 1) ? 0xFFFFu : 0u) | ((tid & 2) ? 0xFFFF0000u : 0u);

    // ---- Q fragments in registers (reused across all k-tiles)
    bf16x8 qf[2][2];
#pragma unroll
    for (int qc = 0; qc < 2; ++qc) {
        const unsigned short* qp = &Qh[hb + (size_t)(q0 + w * 32 + qc * 16 + li) * DH + g * 8];
        qf[qc][0] = *reinterpret_cast<const bf16x8*>(qp);
        qf[qc][1] = *reinterpret_cast<const bf16x8*>(qp + 32);
    }

    // constant all-ones B fragment (bf16 1.0) for the l-sum MFMA
    bf16x8 vones;
#pragma unroll
    for (int j = 0; j < 8; ++j) vones[j] = (short)0x3F80;

    const f32x4 fzero = {0.f, 0.f, 0.f, 0.f};
    f32x4 oacc[2][4];   // [qc][mb]: O[q = qc*16+g*4+reg][d = mb*16+li]
    f32x4 lacc[2];      // [qc]: l-sum for q = qc*16+g*4+reg
#pragma unroll
    for (int qc = 0; qc < 2; ++qc) {
        lacc[qc] = fzero;
#pragma unroll
        for (int mb = 0; mb < 4; ++mb) oacc[qc][mb] = fzero;
    }

    // ---- tile-invariant pre-swizzled staging source offsets (elements)
    int ks_[2], vs_[2];
#pragma unroll
    for (int it = 0; it < 2; ++it) {
        const int c = it * 256 + w * 64 + l;        // dest chunk (linear)
        const int row = c >> 3, cb = (c & 7) ^ (row & 7);
        ks_[it] = row * DH + cb * 8;                // K rows: stride 64
        vs_[it] = row * SS + cb * 8;                // V^T rows: stride 2048
    }
    const unsigned short* Ksrc = Kh + hb;
    const unsigned short* Vsrc = VhT + hb;
    // lane's q-row mask words: row q = q0 + w*32 + qc*16 + li
    const unsigned long long* mrow_p = maskp + ((size_t)(b * SS + q0 + w * 32 + li)) * 32;

#define STAGE(bn, tt) do {                                                      \
    gload16(Ksrc + (size_t)(tt) * 4096 + ks_[0], smem + (bn) * 4096 + w * 512); \
    gload16(Ksrc + (size_t)(tt) * 4096 + ks_[1], smem + (bn) * 4096 + 2048 + w * 512); \
    gload16(Vsrc + (size_t)(tt) * 64 + vs_[0], smem + 8192 + (bn) * 4096 + w * 512);   \
    gload16(Vsrc + (size_t)(tt) * 64 + vs_[1], smem + 8192 + (bn) * 4096 + 2048 + w * 512); \
} while (0)

    STAGE(0, 0);
    __syncthreads();

    int buf = 0;
    for (int t = 0; t < SS / 64; ++t) {
        // prefetch next tile into the other buffer
        if (t < SS / 64 - 1) STAGE(buf ^ 1, t + 1);

        // mask words: one per owned q row (2 per thread; 4 g-lanes share)
        const unsigned long long mw0 = mrow_p[t];
        const unsigned long long mw1 = mrow_p[512 + t];

        // ---- K fragments (b128, even bank spread)
        const char* Kc = (const char*)(smem + buf * 4096);
        bf16x8 kf[4][2];
#pragma unroll
        for (int nb = 0; nb < 4; ++nb)
#pragma unroll
            for (int hh = 0; hh < 2; ++hh)
                kf[nb][hh] = *reinterpret_cast<const bf16x8*>(
                    Kc + (nb * 16 + li) * 128 + (((hh * 4 + g) ^ (li & 7)) << 4));

        // ---- S^T = K.Q^T, raw base-2 exp (no max), P -> A-fragments
        bf16x8 pf[2][2];
#pragma unroll
        for (int qc = 0; qc < 2; ++qc) {
            f32x4 st[4];
#pragma unroll
            for (int nb = 0; nb < 4; ++nb) st[nb] = fzero;
            __builtin_amdgcn_s_setprio(1);
#pragma unroll
            for (int nb = 0; nb < 4; ++nb)
#pragma unroll
                for (int hh = 0; hh < 2; ++hh)
                    st[nb] = MFMA_BF16(kf[nb][hh], qf[qc][hh], st[nb]);
            __builtin_amdgcn_s_setprio(0);

            float e[4][4];
#pragma unroll
            for (int nb = 0; nb < 4; ++nb)
#pragma unroll
                for (int r = 0; r < 4; ++r)
                    e[nb][r] = fexp2(st[nb][r]);

            // pack P (bf16 pairs) then zero masked halves via LUT AND.
            const unsigned long long msh = (qc ? mw1 : mw0) >> (g * 4);
            const unsigned lo = (unsigned)msh, hi = (unsigned)(msh >> 32);
            uint32x4 w0 = {cvtpk(e[0][0], e[0][1]), cvtpk(e[0][2], e[0][3]),
                           cvtpk(e[1][0], e[1][1]), cvtpk(e[1][2], e[1][3])};
            uint32x4 w1 = {cvtpk(e[2][0], e[2][1]), cvtpk(e[2][2], e[2][3]),
                           cvtpk(e[3][0], e[3][1]), cvtpk(e[3][2], e[3][3])};
            w0[0] &= LUT4[lo & 3u];         w0[1] &= LUT4[(lo >> 2) & 3u];
            w0[2] &= LUT4[(lo >> 16) & 3u]; w0[3] &= LUT4[(lo >> 18) & 3u];
            w1[0] &= LUT4[hi & 3u];         w1[1] &= LUT4[(hi >> 2) & 3u];
            w1[2] &= LUT4[(hi >> 16) & 3u]; w1[3] &= LUT4[(hi >> 18) & 3u];
            pf[qc][0] = __builtin_bit_cast(bf16x8, w0);
            pf[qc][1] = __builtin_bit_cast(bf16x8, w1);
        }

        // ---- V^T fragments (b128, identical pattern to K; k pre-permuted)
        const char* Vc = (const char*)(smem + 8192 + buf * 4096);
        bf16x8 vf[4][2];
#pragma unroll
        for (int mb = 0; mb < 4; ++mb)
#pragma unroll
            for (int hh = 0; hh < 2; ++hh)
                vf[mb][hh] = *reinterpret_cast<const bf16x8*>(
                    Vc + (mb * 16 + li) * 128 + (((hh * 4 + g) ^ (li & 7)) << 4));

        // ---- O += P.V ; l += P.1
#pragma unroll
        for (int qc = 0; qc < 2; ++qc) {
            __builtin_amdgcn_s_setprio(1);
#pragma unroll
            for (int hh = 0; hh < 2; ++hh)
#pragma unroll
                for (int mb = 0; mb < 4; ++mb)
                    oacc[qc][mb] = MFMA_BF16(pf[qc][hh], vf[mb][hh], oacc[qc][mb]);
            lacc[qc] = MFMA_BF16(pf[qc][0], vones, lacc[qc]);
            lacc[qc] = MFMA_BF16(pf[qc][1], vones, lacc[qc]);
            __builtin_amdgcn_s_setprio(0);
        }

        __syncthreads();   // drains prefetch vmcnt + protects buffer swap
        buf ^= 1;
    }
#undef STAGE

    // ---- epilogue: normalize (l from lacc, row g*4+r), transpose via LDS
    unsigned short* Ps = smem;   // 128 rows x 64 bf16 = 16 KB, swizzled
#pragma unroll
    for (int qc = 0; qc < 2; ++qc) {
#pragma unroll
        for (int r = 0; r < 4; ++r) {
            const int row = w * 32 + qc * 16 + g * 4 + r;
            const float linv = 1.0f / lacc[qc][r];
#pragma unroll
            for (int mb = 0; mb < 4; ++mb) {
                const int dd = mb * 16 + li;
                *(unsigned short*)((char*)Ps + swzb(row, dd >> 3) + (dd & 7) * 2) =
                    f2b1(oacc[qc][mb][r] * linv);
            }
        }
    }
    __syncthreads();
#pragma unroll
    for (int it = 0; it < 4; ++it) {
        const int c = it * 64 + l;
        const int qrow = w * 32 + (c >> 3), cb = c & 7;
        const bf16x8 ov = *reinterpret_cast<const bf16x8*>((const char*)Ps + swzb(qrow, cb));
        *reinterpret_cast<bf16x8*>(&Ctx[hb + (size_t)(q0 + qrow) * DH + cb * 8]) = ov;
    }
}

// ============================================================================
extern "C" void kernel_launch(void* const* d_in, const int* in_sizes, int n_in,
                              void* d_out, int out_size, void* d_ws, size_t ws_size,
                              hipStream_t stream)
{
    const float* q  = (const float*)d_in[0];
    const float* k  = (const float*)d_in[1];
    const float* v  = (const float*)d_in[2];
    const float* Wq = (const float*)d_in[3];
    const float* bq = (const float*)d_in[4];
    const float* Wk = (const float*)d_in[5];
    const float* bk = (const float*)d_in[6];
    const float* Wv = (const float*)d_in[7];
    const float* bv = (const float*)d_in[8];
    const float* Wo = (const float*)d_in[9];
    const float* bo = (const float*)d_in[10];
    const int* mask = (const int*)d_in[11];
    float* out = (float*)d_out;

    // workspace (bf16 shorts): WT3 3M | WTo 1M | Qb 8M | Kb 8M | Vb 8M |
    // Qh 8M | Kh 8M | maskp 2MB | VhT 8M  == 106 MB (layout proven rounds 9/11).
    // VhT must NOT alias Qb: the fused QKV GEMM reads Qb while writing VhT.
    // Ctx aliases Kb (dead after the fused QKV GEMM completes).
    const size_t M1 = 1048576, M8 = (size_t)MT * DIMM;
    unsigned short* WT3 = (unsigned short*)d_ws;
    unsigned short* WTo = WT3 + 3 * M1;
    unsigned short* Qb  = WTo + M1;
    unsigned short* Kb  = Qb + M8;
    unsigned short* Vb  = Kb + M8;
    unsigned short* Qh  = Vb + M8;
    unsigned short* Kh  = Qh + M8;
    unsigned long long* maskp = (unsigned long long*)(Kh + M8);
    unsigned short* VhT = (unsigned short*)(maskp + (size_t)BB * SS * SS / 64);
    unsigned short* Ctx = Kb;

    dim3 blk(256);

    // one fused preprocessing launch: convert + maskpack + weight transpose
    prep_kernel<<<dim3(78848), blk, 0, stream>>>(q, k, v, Qb, Kb, Vb,
                                                 mask, maskp,
                                                 Wq, Wk, Wv, Wo, WT3, WTo);

    // fused QKV projection (region-sequential, XCD mapping identical to the
    // three separate launches)
    gemm_qkv_kernel<<<dim3(1536), blk, 0, stream>>>(Qb, Kb, Vb, WT3, bq, bk, bv,
                                                    Qh, Kh, VhT);

    dim3 fgrid(NH, SS / 128, BB);   // (16, 16, 4) = 1024 blocks
    flash_kernel<<<fgrid, blk, 0, stream>>>(Qh, Kh, VhT, maskp, Ctx);

    gemm_out_kernel<<<dim3(512), blk, 0, stream>>>(Ctx, WTo, bo, out);
}